// Round 4
// baseline (432.929 us; speedup 1.0000x reference)
//
#include <hip/hip_runtime.h>
#include <math.h>

namespace {
constexpr int   kB       = 8192;
constexpr int   kBlock   = 256;
constexpr int   kWaves   = kBlock / 64;            // 4 waves / block
constexpr int   kRPW     = 2;                      // rows per wave
constexpr int   kGrid    = kB / (kWaves * kRPW);   // 1024 blocks
constexpr int   kChunks  = kB / (64 * 4);          // 32 float4 per lane per row
constexpr int   kNWaves  = kGrid * kWaves;         // 4096 wave partials
constexpr float kMargin   = 0.1f;
constexpr float kThresh   = 0.5f;
constexpr float kScalePos = 2.0f;
constexpr float kScaleNeg = 40.0f;
constexpr float kEps      = 1e-5f;
}

// R4: one ROW per WAVE, zero __syncthreads in the hot kernel.
// R3 failure mode: the compiler emits `s_waitcnt vmcnt(0)` before every
// s_barrier (m97-documented), so the 2 barriers/row drained the cross-row
// prefetch and the memory pipe idled through pass 2 (~117 us vs ~30 us floor).
// Here the full row lives in one wave's registers (32 float4 = 128 VGPRs),
// reductions are 6 shfl_xor butterflies (no vmcnt interaction), and waves
// drift independently -> loads stay in flight continuously from pure TLP.
// __launch_bounds__(256,2): 256-VGPR budget so the 128-reg row buffer never
// spills; actual ~160 VGPRs still gives 3 waves/SIMD.
__global__ __launch_bounds__(kBlock, 2) void ms_rows_kernel(
    const float* __restrict__ sim,
    const int*   __restrict__ labels,
    float*       __restrict__ ws)
{
  const int tid  = threadIdx.x;
  const int wave = tid >> 6;
  const int lane = tid & 63;
  const int wid  = blockIdx.x * kWaves + wave;

  float wave_loss = 0.0f;

  #pragma unroll
  for (int rr = 0; rr < kRPW; ++rr) {
    const int row = wid * kRPW + rr;
    const int ml  = labels[row];                   // wave-uniform
    const float* __restrict__ srow = sim + (size_t)row * kB;

    // ---- Issue all 32 dwordx4 for this row (deep MLP, no barriers ahead) ----
    float4 buf[kChunks];
    #pragma unroll
    for (int k = 0; k < kChunks; ++k)
      buf[k] = *reinterpret_cast<const float4*>(srow + k * 256 + lane * 4);

    // ---- Pass 1: same-label bitmask (labels L1/L2-hot) + hardest pos/neg ----
    unsigned int msk[kChunks / 8] = {0, 0, 0, 0};  // 128 bits/lane
    float min_pos =  INFINITY;
    float max_neg = -INFINITY;
    #pragma unroll
    for (int k = 0; k < kChunks; ++k) {
      const int4   l4 = *reinterpret_cast<const int4*>(labels + k * 256 + lane * 4);
      const float4 v  = buf[k];
      const float xs[4] = {v.x, v.y, v.z, v.w};
      const int   ls[4] = {l4.x, l4.y, l4.z, l4.w};
      #pragma unroll
      for (int c = 0; c < 4; ++c) {
        const bool  same = (ls[c] == ml);
        msk[k >> 3] |= (unsigned)same << ((k & 7) * 4 + c);
        const float x = xs[c];
        min_pos = fminf(min_pos, (same && x < 1.0f - kEps) ? x : INFINITY);
        max_neg = fmaxf(max_neg, same ? -INFINITY : x);
      }
    }
    // Wave-only reduce + broadcast (butterfly leaves result in all lanes).
    #pragma unroll
    for (int off = 32; off > 0; off >>= 1) {
      min_pos = fminf(min_pos, __shfl_xor(min_pos, off, 64));
      max_neg = fmaxf(max_neg, __shfl_xor(max_neg, off, 64));
    }

    // ---- Pass 2 (registers): mined exp-sums, one v_exp_f32 per element ----
    // exp args in [-60, 20]: never underflows -> pos_sum>0 <=> any(sel_pos).
    float ps = 0.0f, ns = 0.0f;
    #pragma unroll
    for (int k = 0; k < kChunks; ++k) {
      const float4 v = buf[k];
      const float xs[4] = {v.x, v.y, v.z, v.w};
      #pragma unroll
      for (int c = 0; c < 4; ++c) {
        const bool  same = (msk[k >> 3] >> ((k & 7) * 4 + c)) & 1u;
        const float x = xs[c];
        const float a = same ? -kScalePos : kScaleNeg;
        const float e = __expf(a * (x - kThresh));
        ps += (same && x < 1.0f - kEps && x - kMargin < max_neg) ? e : 0.0f;
        ns += (!same && x + kMargin > min_pos) ? e : 0.0f;
      }
    }
    #pragma unroll
    for (int off = 32; off > 0; off >>= 1) {
      ps += __shfl_xor(ps, off, 64);
      ns += __shfl_xor(ns, off, 64);
    }
    if (ps > 0.0f && ns > 0.0f) {
      wave_loss += log1pf(ps) * (1.0f / kScalePos)
                 + log1pf(ns) * (1.0f / kScaleNeg);
    }
  }

  if (lane == 0) ws[wid] = wave_loss;              // no atomics
}

// Tiny second kernel: sum the 4096 wave partials, scale, write the scalar.
__global__ __launch_bounds__(256) void ms_reduce_kernel(
    const float* __restrict__ ws, float* __restrict__ out)
{
  const int tid = threadIdx.x;
  float s = 0.0f;
  #pragma unroll
  for (int i = tid; i < kNWaves; i += 256) s += ws[i];
  #pragma unroll
  for (int off = 32; off > 0; off >>= 1) s += __shfl_xor(s, off, 64);
  __shared__ float sm[4];
  if ((tid & 63) == 0) sm[tid >> 6] = s;
  __syncthreads();
  if (tid == 0)
    out[0] = (sm[0] + sm[1] + sm[2] + sm[3]) * (1.0f / (float)kB);
}

extern "C" void kernel_launch(void* const* d_in, const int* in_sizes, int n_in,
                              void* d_out, int out_size, void* d_ws, size_t ws_size,
                              hipStream_t stream) {
  const float* sim    = (const float*)d_in[0];
  const int*   labels = (const int*)d_in[1];
  float*       ws     = (float*)d_ws;              // 4096 floats, fully rewritten
  float*       out    = (float*)d_out;             // written by reduce kernel

  ms_rows_kernel<<<dim3(kGrid), dim3(kBlock), 0, stream>>>(sim, labels, ws);
  ms_reduce_kernel<<<dim3(1), dim3(256), 0, stream>>>(ws, out);
}